// Round 3
// baseline (352.201 us; speedup 1.0000x reference)
//
#include <hip/hip_runtime.h>
#include <hip/hip_bf16.h>

#define TT 8
#define CC 128
#define DD 64
#define HWp 9216
#define PP 16
#define NBT 288         // tile-PAIRS per batch image: HWp / (2*PP)
#define XB_STRIDE 152   // bf16 elems per staged row (128 + 24 pad) = 304B
#define QKV_STRIDE 264  // bf16 elems per (t,p) row (256 + 8 pad) = 528B, 16B-aligned

typedef __attribute__((ext_vector_type(8))) short short8;
typedef __attribute__((ext_vector_type(4))) short short4v;
typedef __attribute__((ext_vector_type(4))) float floatx4;
typedef __attribute__((ext_vector_type(4))) unsigned uint4v;

__device__ __forceinline__ short f2bf(float f) {
    __hip_bfloat16 h = __float2bfloat16(f);
    return __builtin_bit_cast(short, h);
}
__device__ __forceinline__ float u2f(unsigned u) {
    return __builtin_bit_cast(float, u);
}
// short8 (8 bf16) -> 8 floats, 1 VALU op per element (shift / mask).
__device__ __forceinline__ void bf8_to_f(short8 v, float* f) {
    uint4v u = __builtin_bit_cast(uint4v, v);
#pragma unroll
    for (int i = 0; i < 4; ++i) {
        f[2 * i]     = u2f(u[i] << 16);
        f[2 * i + 1] = u2f(u[i] & 0xffff0000u);
    }
}

// Raw barrier: NO vmcnt drain (global prefetch stays in flight across it).
__device__ __forceinline__ void bar_raw() {
    __builtin_amdgcn_sched_barrier(0);
    __builtin_amdgcn_s_barrier();
    __builtin_amdgcn_sched_barrier(0);
}
// Producer barrier: drain LDS ops only (lgkmcnt), then barrier.
__device__ __forceinline__ void bar_lds() {
    __builtin_amdgcn_sched_barrier(0);
    asm volatile("s_waitcnt lgkmcnt(0)" ::: "memory");
    __builtin_amdgcn_s_barrier();
    __builtin_amdgcn_sched_barrier(0);
}

// block = 512 threads = 8 waves; LDS ~77KB -> 2 blocks/CU (LDS-limited).
// Each block processes TWO adjacent 16-pixel tiles, pipelined: tile1's first
// x-loads are in flight across tile0's attention phase.
__global__ __launch_bounds__(512, 4) void ta_kernel(
    const float* __restrict__ x,
    const float* __restrict__ Wq, const float* __restrict__ bq,
    const float* __restrict__ Wk, const float* __restrict__ bk,
    const float* __restrict__ Wv, const float* __restrict__ bv,
    float* __restrict__ out)
{
    __shared__ short xb[32 * XB_STRIDE];            // 9728 B (2 t x 16 p rows)
    __shared__ short qkv[TT * PP * QKV_STRIDE];     // 67584 B (row = t*16 + p)

    const int tid  = threadIdx.x;
    const int wave = tid >> 6;      // 0..7
    const int lane = tid & 63;
    const int quad = lane >> 4;
    const int l16  = lane & 15;

    const int blk = blockIdx.x;
    const int b   = blk / NBT;
    const int p0b = (blk % NBT) * (2 * PP);

    // ---- Preload weight A-fragments + biases into registers ----
    // Stacked f rows: [0,64) = Wq, [64,128) = Wk, [128,256) = Wv.
    // Wave w owns f-tiles 2w, 2w+1. A-frag (16x16x32): A[m=lane&15][k=quad*8+j].
    short8 wfrag[2][4];   // [tile][kchunk]
    float  bias[2][4];    // [tile][reg]
#pragma unroll
    for (int i = 0; i < 2; ++i) {
        const int f0  = (wave * 2 + i) * 16;
        const int row = f0 + l16;
        const float* wrow;
        if (row < DD)            wrow = Wq + row * CC;
        else if (row < 2 * DD)   wrow = Wk + (row - DD) * CC;
        else                     wrow = Wv + (row - 2 * DD) * CC;
#pragma unroll
        for (int kc = 0; kc < 4; ++kc) {
            const float* src = wrow + kc * 32 + quad * 8;
            short8 v;
#pragma unroll
            for (int j = 0; j < 8; ++j) v[j] = f2bf(src[j]);
            wfrag[i][kc] = v;
        }
        const int fb = f0 + quad * 4;   // rows this lane accumulates (D layout)
        const float* bsrc; int off;
        if (fb < DD)            { bsrc = bq; off = fb; }
        else if (fb < 2 * DD)   { bsrc = bk; off = fb - DD; }
        else                    { bsrc = bv; off = fb - 2 * DD; }
#pragma unroll
        for (int r = 0; r < 4; ++r) bias[i][r] = bsrc[off + r];
    }

    // ---- 8 projection rounds (2 tiles x 4 t-pairs), attention after rounds 3,7.
    // 512 threads: each loads one float4 (c0, p4..p4+3) for both t's of a pair.
    const int c0 = tid >> 2;            // 0..127
    const int p4 = (tid & 3) * 4;       // 0,4,8,12
    const float* xsrc = x + ((size_t)(b * TT) * CC + c0) * HWp + p0b + p4;

    float4 cur0 = *(const float4*)xsrc;
    float4 cur1 = *(const float4*)(xsrc + (size_t)CC * HWp);
    float4 nxt0 = cur0, nxt1 = cur1;

    for (int r = 0; r < 8; ++r) {
        const int tp = r & 3;
        if (r < 7) {
            // Prefetch next round's t-pair (round 3 prefetches tile1's t0/t1,
            // which stays in flight across tile0's whole attention phase).
            const int nl = (r + 1) >> 2, np = (r + 1) & 3;
            const float* ns = xsrc + nl * PP + (size_t)(2 * np) * CC * HWp;
            nxt0 = *(const float4*)ns;
            nxt1 = *(const float4*)(ns + (size_t)CC * HWp);
        }

        bar_raw();   // xb consumers of previous round are done (no vmcnt drain)
        xb[(p4 + 0) * XB_STRIDE + c0] = f2bf(cur0.x);
        xb[(p4 + 1) * XB_STRIDE + c0] = f2bf(cur0.y);
        xb[(p4 + 2) * XB_STRIDE + c0] = f2bf(cur0.z);
        xb[(p4 + 3) * XB_STRIDE + c0] = f2bf(cur0.w);
        xb[(16 + p4 + 0) * XB_STRIDE + c0] = f2bf(cur1.x);
        xb[(16 + p4 + 1) * XB_STRIDE + c0] = f2bf(cur1.y);
        xb[(16 + p4 + 2) * XB_STRIDE + c0] = f2bf(cur1.z);
        xb[(16 + p4 + 3) * XB_STRIDE + c0] = f2bf(cur1.w);
        bar_lds();   // xb visible; prefetch loads remain in flight

        // D = A(W: f x c) * B(x: c x p), two B-tiles (t-even, t-odd).
        // B-frag: B[k=quad*8+j][n=lane&15], contiguous 8 bf16 (ds_read_b128).
        floatx4 acc[2][2];   // [t-tile][w-tile]
#pragma unroll
        for (int tt = 0; tt < 2; ++tt)
#pragma unroll
            for (int i = 0; i < 2; ++i)
#pragma unroll
                for (int rr = 0; rr < 4; ++rr) acc[tt][i][rr] = 0.f;
#pragma unroll
        for (int kc = 0; kc < 4; ++kc) {
            short8 xf0 = *(const short8*)&xb[l16 * XB_STRIDE + kc * 32 + quad * 8];
            short8 xf1 = *(const short8*)&xb[(16 + l16) * XB_STRIDE + kc * 32 + quad * 8];
            acc[0][0] = __builtin_amdgcn_mfma_f32_16x16x32_bf16(wfrag[0][kc], xf0, acc[0][0], 0, 0, 0);
            acc[0][1] = __builtin_amdgcn_mfma_f32_16x16x32_bf16(wfrag[1][kc], xf0, acc[0][1], 0, 0, 0);
            acc[1][0] = __builtin_amdgcn_mfma_f32_16x16x32_bf16(wfrag[0][kc], xf1, acc[1][0], 0, 0, 0);
            acc[1][1] = __builtin_amdgcn_mfma_f32_16x16x32_bf16(wfrag[1][kc], xf1, acc[1][1], 0, 0, 0);
        }
        // D layout: col(n=p) = lane&15, row(m=f) = quad*4 + r.
#pragma unroll
        for (int tt = 0; tt < 2; ++tt)
#pragma unroll
            for (int i = 0; i < 2; ++i) {
                const int f0 = (wave * 2 + i) * 16 + quad * 4;
                short4v o;
#pragma unroll
                for (int rr = 0; rr < 4; ++rr) o[rr] = f2bf(acc[tt][i][rr] + bias[i][rr]);
                *(short4v*)&qkv[((2 * tp + tt) * PP + l16) * QKV_STRIDE + f0] = o;
            }
        cur0 = nxt0; cur1 = nxt1;

        if (tp == 3) {
            bar_lds();   // all qkv writes visible; tile1 prefetch stays in flight

            // ---- Attention for tile (r>>2): 64 thr/pixel = (tq=wave)x(quad).
            const int p0t = p0b + (r >> 2) * PP;
            const int p   = l16;
            const int tq  = wave;
            const short* prow = &qkv[p * QKV_STRIDE];

            float qv[16];
            {
                const short* q8 = prow + (tq * PP) * QKV_STRIDE + quad * 16;
                bf8_to_f(*(const short8*)q8, qv);
                bf8_to_f(*(const short8*)(q8 + 8), qv + 8);
            }
            // Scores: half-batches of 4 s -> 8 ds_read_b128 in flight at once.
            float sc[TT];
#pragma unroll
            for (int h = 0; h < 2; ++h) {
                short8 kr[8];
#pragma unroll
                for (int s4 = 0; s4 < 4; ++s4) {
                    const short* k8 = prow + ((h * 4 + s4) * PP) * QKV_STRIDE + DD + quad * 16;
                    kr[2 * s4]     = *(const short8*)k8;
                    kr[2 * s4 + 1] = *(const short8*)(k8 + 8);
                }
#pragma unroll
                for (int s4 = 0; s4 < 4; ++s4) {
                    float kv[16];
                    bf8_to_f(kr[2 * s4], kv);
                    bf8_to_f(kr[2 * s4 + 1], kv + 8);
                    float a = 0.f;
#pragma unroll
                    for (int j = 0; j < 16; ++j) a = fmaf(qv[j], kv[j], a);
                    sc[h * 4 + s4] = a;
                }
            }
            // reduce partial dots across the 4 quads (lane bits 4,5)
#pragma unroll
            for (int m = 16; m <= 32; m <<= 1)
#pragma unroll
                for (int s = 0; s < TT; ++s) sc[s] += __shfl_xor(sc[s], m, 64);

            float mx = sc[0];
#pragma unroll
            for (int s = 1; s < TT; ++s) mx = fmaxf(mx, sc[s]);
            float sum = 0.f;
#pragma unroll
            for (int s = 0; s < TT; ++s) {
                float e = __expf((sc[s] - mx) * 0.125f);   // fold 1/sqrt(64)
                sc[s] = e; sum += e;
            }
            const float inv = 1.f / sum;
#pragma unroll
            for (int s = 0; s < TT; ++s) sc[s] *= inv;

            // PV: thread owns e = k*32 + quad*8 + j (quad-interleaved chunks).
            float o[32];
#pragma unroll
            for (int j = 0; j < 32; ++j) o[j] = 0.f;
#pragma unroll
            for (int s = 0; s < TT; ++s) {
                const short* vrow = prow + (s * PP) * QKV_STRIDE + 2 * DD + quad * 8;
                short8 v0 = *(const short8*)(vrow);
                short8 v1 = *(const short8*)(vrow + 32);
                short8 v2 = *(const short8*)(vrow + 64);
                short8 v3 = *(const short8*)(vrow + 96);
                const float a = sc[s];
                float vv[8];
                bf8_to_f(v0, vv);
#pragma unroll
                for (int j = 0; j < 8; ++j) o[j] = fmaf(a, vv[j], o[j]);
                bf8_to_f(v1, vv);
#pragma unroll
                for (int j = 0; j < 8; ++j) o[8 + j] = fmaf(a, vv[j], o[8 + j]);
                bf8_to_f(v2, vv);
#pragma unroll
                for (int j = 0; j < 8; ++j) o[16 + j] = fmaf(a, vv[j], o[16 + j]);
                bf8_to_f(v3, vv);
#pragma unroll
                for (int j = 0; j < 8; ++j) o[24 + j] = fmaf(a, vv[j], o[24 + j]);
            }
            // out[b][tq][e][hw]; lanes 0..15 = consecutive pixels -> 64B lines.
            // Stores are fire-and-forget; raw barriers never drain them.
            float* op = out + ((size_t)((b * TT + tq) * CC + quad * 8)) * HWp + p0t + p;
#pragma unroll
            for (int k = 0; k < 4; ++k)
#pragma unroll
                for (int j = 0; j < 8; ++j)
                    op[(size_t)(k * 32 + j) * HWp] = o[k * 8 + j];
        }
    }
}

extern "C" void kernel_launch(void* const* d_in, const int* in_sizes, int n_in,
                              void* d_out, int out_size, void* d_ws, size_t ws_size,
                              hipStream_t stream) {
    const float* x  = (const float*)d_in[0];
    const float* Wq = (const float*)d_in[1];
    const float* bq = (const float*)d_in[2];
    const float* Wk = (const float*)d_in[3];
    const float* bk = (const float*)d_in[4];
    const float* Wv = (const float*)d_in[5];
    const float* bv = (const float*)d_in[6];
    float* out = (float*)d_out;

    const int blocks = 4 * NBT;   // B=4 x 288 tile-pairs = 1152
    ta_kernel<<<blocks, 512, 0, stream>>>(x, Wq, bq, Wk, bk, Wv, bv, out);
}

// Round 4
// 327.382 us; speedup vs baseline: 1.0758x; 1.0758x over previous
//
#include <hip/hip_runtime.h>
#include <hip/hip_bf16.h>

#define TT 8
#define CC 128
#define DD 64
#define HWp 9216
#define PP 16
#define NTILE 576       // HWp / PP
#define XB_STRIDE 152   // bf16 elems per staged row (128 + 24 pad) = 304B
#define QKV_STRIDE 264  // bf16 elems per (t,p) row (256 + 8 pad) = 528B, 16B-aligned

typedef __attribute__((ext_vector_type(8))) short short8;
typedef __attribute__((ext_vector_type(4))) short short4v;
typedef __attribute__((ext_vector_type(4))) float floatx4;
typedef __attribute__((ext_vector_type(4))) unsigned uint4v;

__device__ __forceinline__ short f2bf(float f) {
    __hip_bfloat16 h = __float2bfloat16(f);
    return __builtin_bit_cast(short, h);
}
__device__ __forceinline__ float u2f(unsigned u) {
    return __builtin_bit_cast(float, u);
}
// short8 (8 bf16) -> 8 floats, 1 VALU op per element (shift / mask).
__device__ __forceinline__ void bf8_to_f(short8 v, float* f) {
    uint4v u = __builtin_bit_cast(uint4v, v);
#pragma unroll
    for (int i = 0; i < 4; ++i) {
        f[2 * i]     = u2f(u[i] << 16);
        f[2 * i + 1] = u2f(u[i] & 0xffff0000u);
    }
}

// block = 512 threads = 8 waves; LDS ~77KB -> 2 blocks/CU (LDS-limited).
__global__ __launch_bounds__(512, 4) void ta_kernel(
    const float* __restrict__ x,
    const float* __restrict__ Wq, const float* __restrict__ bq,
    const float* __restrict__ Wk, const float* __restrict__ bk,
    const float* __restrict__ Wv, const float* __restrict__ bv,
    float* __restrict__ out)
{
    __shared__ short xb[32 * XB_STRIDE];            // 9728 B (2 t x 16 p rows)
    __shared__ short qkv[TT * PP * QKV_STRIDE];     // 67584 B (row = t*16 + p)

    const int tid  = threadIdx.x;
    const int wave = tid >> 6;      // 0..7
    const int lane = tid & 63;
    const int quad = lane >> 4;
    const int l16  = lane & 15;

    const int blk = blockIdx.x;
    const int b   = blk / NTILE;
    const int p0  = (blk % NTILE) * PP;

    // ---- Issue ALL x loads upfront: 8 float4 = this thread's entire share.
    // One vmcnt exposure at the first barrier instead of 8 per-round stalls.
    const int c0 = tid >> 2;            // 0..127
    const int p4 = (tid & 3) * 4;       // 0,4,8,12
    const float* xsrc = x + ((size_t)(b * TT) * CC + c0) * HWp + p0 + p4;
    float4 xr[TT];
#pragma unroll
    for (int t = 0; t < TT; ++t)
        xr[t] = *(const float4*)(xsrc + (size_t)t * CC * HWp);

    // ---- Preload weight A-fragments + biases into registers ----
    // (overlaps the x-load latency; weights are L2-hot after the first blocks)
    // Stacked f rows: [0,64) = Wq, [64,128) = Wk, [128,256) = Wv.
    // Wave w owns f-tiles 2w, 2w+1. A-frag (16x16x32): A[m=lane&15][k=quad*8+j].
    short8 wfrag[2][4];   // [tile][kchunk]
    float  bias[2][4];    // [tile][reg]
#pragma unroll
    for (int i = 0; i < 2; ++i) {
        const int f0  = (wave * 2 + i) * 16;
        const int row = f0 + l16;
        const float* wrow;
        if (row < DD)            wrow = Wq + row * CC;
        else if (row < 2 * DD)   wrow = Wk + (row - DD) * CC;
        else                     wrow = Wv + (row - 2 * DD) * CC;
#pragma unroll
        for (int kc = 0; kc < 4; ++kc) {
            const float* src = wrow + kc * 32 + quad * 8;
            short8 v;
#pragma unroll
            for (int j = 0; j < 8; ++j) v[j] = f2bf(src[j]);
            wfrag[i][kc] = v;
        }
        const int fb = f0 + quad * 4;   // rows this lane accumulates (D layout)
        const float* bsrc; int off;
        if (fb < DD)            { bsrc = bq; off = fb; }
        else if (fb < 2 * DD)   { bsrc = bk; off = fb - DD; }
        else                    { bsrc = bv; off = fb - 2 * DD; }
#pragma unroll
        for (int r = 0; r < 4; ++r) bias[i][r] = bsrc[off + r];
    }

    // ---- Projection: t-PAIR per round, 4 rounds, fully unrolled so xr[]
    // indices are compile-time (registers, not scratch).
#pragma unroll
    for (int tp = 0; tp < 4; ++tp) {
        const float4 cur0 = xr[2 * tp];
        const float4 cur1 = xr[2 * tp + 1];

        __syncthreads();   // xb from previous round fully consumed
        xb[(p4 + 0) * XB_STRIDE + c0] = f2bf(cur0.x);
        xb[(p4 + 1) * XB_STRIDE + c0] = f2bf(cur0.y);
        xb[(p4 + 2) * XB_STRIDE + c0] = f2bf(cur0.z);
        xb[(p4 + 3) * XB_STRIDE + c0] = f2bf(cur0.w);
        xb[(16 + p4 + 0) * XB_STRIDE + c0] = f2bf(cur1.x);
        xb[(16 + p4 + 1) * XB_STRIDE + c0] = f2bf(cur1.y);
        xb[(16 + p4 + 2) * XB_STRIDE + c0] = f2bf(cur1.z);
        xb[(16 + p4 + 3) * XB_STRIDE + c0] = f2bf(cur1.w);
        __syncthreads();

        // D = A(W: f x c) * B(x: c x p), two B-tiles (t-even, t-odd).
        // B-frag: B[k=quad*8+j][n=lane&15], contiguous 8 bf16 (ds_read_b128).
        floatx4 acc[2][2];   // [t-tile][w-tile]
#pragma unroll
        for (int tt = 0; tt < 2; ++tt)
#pragma unroll
            for (int i = 0; i < 2; ++i)
#pragma unroll
                for (int r = 0; r < 4; ++r) acc[tt][i][r] = 0.f;
#pragma unroll
        for (int kc = 0; kc < 4; ++kc) {
            short8 xf0 = *(const short8*)&xb[l16 * XB_STRIDE + kc * 32 + quad * 8];
            short8 xf1 = *(const short8*)&xb[(16 + l16) * XB_STRIDE + kc * 32 + quad * 8];
            acc[0][0] = __builtin_amdgcn_mfma_f32_16x16x32_bf16(wfrag[0][kc], xf0, acc[0][0], 0, 0, 0);
            acc[0][1] = __builtin_amdgcn_mfma_f32_16x16x32_bf16(wfrag[1][kc], xf0, acc[0][1], 0, 0, 0);
            acc[1][0] = __builtin_amdgcn_mfma_f32_16x16x32_bf16(wfrag[0][kc], xf1, acc[1][0], 0, 0, 0);
            acc[1][1] = __builtin_amdgcn_mfma_f32_16x16x32_bf16(wfrag[1][kc], xf1, acc[1][1], 0, 0, 0);
        }
        // D layout: col(n=p) = lane&15, row(m=f) = quad*4 + r.
#pragma unroll
        for (int tt = 0; tt < 2; ++tt)
#pragma unroll
            for (int i = 0; i < 2; ++i) {
                const int f0 = (wave * 2 + i) * 16 + quad * 4;
                short4v o;
#pragma unroll
                for (int r = 0; r < 4; ++r) o[r] = f2bf(acc[tt][i][r] + bias[i][r]);
                *(short4v*)&qkv[((2 * tp + tt) * PP + l16) * QKV_STRIDE + f0] = o;
            }
    }
    __syncthreads();

    // ---- Attention: 64 threads/pixel = (tq = wave) x (quad = d/e slice).
    // Scores: each thread does 16 of 64 d's, shfl_xor-reduced across quads.
    {
        const int p  = l16;
        const int tq = wave;

        const short* prow = &qkv[p * QKV_STRIDE];   // row (s,p) = prow + s*16*QKV_STRIDE

        // Q read + ALL 16 K reads issued before any score FMA (one latency hit).
        float qv[16];
        {
            const short* q8 = prow + (tq * PP) * QKV_STRIDE + quad * 16;
            bf8_to_f(*(const short8*)q8, qv);
            bf8_to_f(*(const short8*)(q8 + 8), qv + 8);
        }
        short8 kr[16];
#pragma unroll
        for (int s = 0; s < TT; ++s) {
            const short* k8 = prow + (s * PP) * QKV_STRIDE + DD + quad * 16;
            kr[2 * s]     = *(const short8*)k8;
            kr[2 * s + 1] = *(const short8*)(k8 + 8);
        }
        float sc[TT];
#pragma unroll
        for (int s = 0; s < TT; ++s) {
            float kv[16];
            bf8_to_f(kr[2 * s], kv);
            bf8_to_f(kr[2 * s + 1], kv + 8);
            float a = 0.f;
#pragma unroll
            for (int j = 0; j < 16; ++j) a = fmaf(qv[j], kv[j], a);
            sc[s] = a;
        }
        // reduce partial dots across the 4 quads (lane bits 4,5)
#pragma unroll
        for (int m = 16; m <= 32; m <<= 1)
#pragma unroll
            for (int s = 0; s < TT; ++s) sc[s] += __shfl_xor(sc[s], m, 64);

        // softmax: tree max / tree sum (short dependency chains)
        const float mx = fmaxf(fmaxf(fmaxf(sc[0], sc[1]), fmaxf(sc[2], sc[3])),
                               fmaxf(fmaxf(sc[4], sc[5]), fmaxf(sc[6], sc[7])));
#pragma unroll
        for (int s = 0; s < TT; ++s) sc[s] = __expf((sc[s] - mx) * 0.125f);
        const float sum = (sc[0] + sc[1]) + (sc[2] + sc[3])
                        + ((sc[4] + sc[5]) + (sc[6] + sc[7]));
        const float inv = 1.f / sum;
#pragma unroll
        for (int s = 0; s < TT; ++s) sc[s] *= inv;

        // PV: thread owns e = k*32 + quad*8 + j; 1-ahead register pipeline:
        // read V[s+1]'s 4 rows while FMA-ing V[s] (static va/vb selection).
        float o[32];
#pragma unroll
        for (int j = 0; j < 32; ++j) o[j] = 0.f;

        short8 va[4], vb[4];
        {
            const short* vrow = prow + 2 * DD + quad * 8;   // s = 0
#pragma unroll
            for (int k = 0; k < 4; ++k) va[k] = *(const short8*)(vrow + k * 32);
        }
#pragma unroll
        for (int s = 0; s < TT; ++s) {
            if (s < TT - 1) {
                const short* vrow = prow + ((s + 1) * PP) * QKV_STRIDE + 2 * DD + quad * 8;
                if (s & 1) {
#pragma unroll
                    for (int k = 0; k < 4; ++k) va[k] = *(const short8*)(vrow + k * 32);
                } else {
#pragma unroll
                    for (int k = 0; k < 4; ++k) vb[k] = *(const short8*)(vrow + k * 32);
                }
            }
            const float a = sc[s];
#pragma unroll
            for (int k = 0; k < 4; ++k) {
                float vv[8];
                bf8_to_f((s & 1) ? vb[k] : va[k], vv);
#pragma unroll
                for (int j = 0; j < 8; ++j) o[k * 8 + j] = fmaf(a, vv[j], o[k * 8 + j]);
            }
        }
        // out[b][tq][e][hw]; lanes 0..15 = consecutive pixels -> full 64B lines
        float* op = out + ((size_t)((b * TT + tq) * CC + quad * 8)) * HWp + p0 + p;
#pragma unroll
        for (int k = 0; k < 4; ++k)
#pragma unroll
            for (int j = 0; j < 8; ++j)
                op[(size_t)(k * 32 + j) * HWp] = o[k * 8 + j];
    }
}

extern "C" void kernel_launch(void* const* d_in, const int* in_sizes, int n_in,
                              void* d_out, int out_size, void* d_ws, size_t ws_size,
                              hipStream_t stream) {
    const float* x  = (const float*)d_in[0];
    const float* Wq = (const float*)d_in[1];
    const float* bq = (const float*)d_in[2];
    const float* Wk = (const float*)d_in[3];
    const float* bk = (const float*)d_in[4];
    const float* Wv = (const float*)d_in[5];
    const float* bv = (const float*)d_in[6];
    float* out = (float*)d_out;

    const int blocks = 4 * NTILE;   // B=4 x 576 pixel-tiles = 2304
    ta_kernel<<<blocks, 512, 0, stream>>>(x, Wq, bq, Wk, bk, Wv, bv, out);
}